// Round 1
// baseline (174.605 us; speedup 1.0000x reference)
//
#include <hip/hip_runtime.h>
#include <math.h>

#define N_NODES 2048
#define ND 64
#define TI 32
#define JT 64

// Stage 1: Wh = X@Ws (per-row), s = Wh·a[:64], t = Wh·a[64:]
__global__ void gat_stage1(const float* __restrict__ X, const float* __restrict__ Ws,
                           const float* __restrict__ av, float* __restrict__ Wh,
                           float* __restrict__ sv, float* __restrict__ tvv) {
    __shared__ float wsT[64][68];   // Ws transposed: wsT[d][f]
    __shared__ float xr[4][64];
    int tid = threadIdx.x;
#pragma unroll
    for (int k = 0; k < 16; ++k) {
        int idx = k * 256 + tid;      // 0..4095 over Ws[f][d]
        int f = idx >> 6, d = idx & 63;
        wsT[d][f] = Ws[idx];
    }
    int wave = tid >> 6, lane = tid & 63;
    long row = (long)blockIdx.x * 4 + wave;   // 0..16383
    xr[wave][lane] = X[row * 64 + lane];
    __syncthreads();
    float acc = 0.f;
#pragma unroll
    for (int f = 0; f < 64; f += 4) {
        float4 xv = *reinterpret_cast<const float4*>(&xr[wave][f]);
        float4 wv = *reinterpret_cast<const float4*>(&wsT[lane][f]);
        acc += xv.x * wv.x + xv.y * wv.y + xv.z * wv.z + xv.w * wv.w;
    }
    Wh[row * 64 + lane] = acc;
    float s = acc * av[lane];
    float t2 = acc * av[64 + lane];
#pragma unroll
    for (int off = 32; off; off >>= 1) {
        s += __shfl_xor(s, off, 64);
        t2 += __shfl_xor(t2, off, 64);
    }
    if (lane == 0) { sv[row] = s; tvv[row] = t2; }
}

// Stage 2: fused masked-softmax attention + PV + ELU, flash-style over j-chunks.
// Block: 256 threads; output tile TI=32 rows x 64 cols; chunk JT=64 j's.
__global__ void gat_stage2(const float* __restrict__ A, const float* __restrict__ Wh,
                           const float* __restrict__ sv, const float* __restrict__ tvv,
                           float* __restrict__ H) {
    __shared__ float wt[JT][34];   // w transposed [j][i], stride 34 (b64-aligned reads)
    __shared__ float wh[JT][68];   // Wh chunk [j][d], stride 68 (b128-aligned reads)
    __shared__ float ssm[TI];
    int tid = threadIdx.x;
    int bid = blockIdx.x;
    int b = bid >> 6;              // 64 i-tiles per batch
    int i0 = (bid & 63) * TI;
    const float* Ab = A + ((long)b * N_NODES + i0) * N_NODES;
    const float* Whb = Wh + (long)b * N_NODES * ND;
    const float* tb = tvv + (long)b * N_NODES;
    if (tid < TI) ssm[tid] = sv[(long)b * N_NODES + i0 + tid];
    int tx = tid & 15, ty = tid >> 4;   // phase B: d-group, i-group
    int jl = tid & 63, ig = tid >> 6;   // phase A: j lane, i group
    float acc[2][4] = {{0.f, 0.f, 0.f, 0.f}, {0.f, 0.f, 0.f, 0.f}};
    float wsum0 = 0.f, wsum1 = 0.f;
    __syncthreads();

    for (int jb = 0; jb < N_NODES; jb += JT) {
        // stage Wh chunk -> LDS (coalesced float4)
#pragma unroll
        for (int q = 0; q < 4; ++q) {
            int f4 = q * 256 + tid;          // 0..1023 float4s
            int j = f4 >> 4;
            int c = (f4 & 15) << 2;
            float4 v = *reinterpret_cast<const float4*>(Whb + (long)(jb + j) * ND + c);
            *reinterpret_cast<float4*>(&wh[j][c]) = v;
        }
        // phase A: weights w_ij = A ? exp(leaky(s_i + t_j)) : 0
        float tj = tb[jb + jl];
#pragma unroll
        for (int p = 0; p < 8; ++p) {
            int il = p * 4 + ig;
            float avv = Ab[(long)il * N_NODES + jb + jl];   // coalesced
            float e = ssm[il] + tj;
            e = e > 0.f ? e : 0.2f * e;
            wt[jl][il] = (avv > 0.f) ? __expf(e) : 0.f;
        }
        __syncthreads();
        // phase B: register-tiled outer product, acc[2][4] per thread
#pragma unroll 8
        for (int j = 0; j < JT; ++j) {
            float2 wv = *reinterpret_cast<const float2*>(&wt[j][ty << 1]);
            float4 hv = *reinterpret_cast<const float4*>(&wh[j][tx << 2]);
            acc[0][0] += wv.x * hv.x; acc[0][1] += wv.x * hv.y;
            acc[0][2] += wv.x * hv.z; acc[0][3] += wv.x * hv.w;
            acc[1][0] += wv.y * hv.x; acc[1][1] += wv.y * hv.y;
            acc[1][2] += wv.y * hv.z; acc[1][3] += wv.y * hv.w;
            wsum0 += wv.x; wsum1 += wv.y;
        }
        __syncthreads();
    }

    float inv0 = 1.f / wsum0, inv1 = 1.f / wsum1;
    long orow0 = (long)b * N_NODES + i0 + (ty << 1);
#pragma unroll
    for (int c = 0; c < 4; ++c) {
        float v0 = acc[0][c] * inv0;
        float v1 = acc[1][c] * inv1;
        v0 = v0 > 0.f ? v0 : expm1f(v0);
        v1 = v1 > 0.f ? v1 : expm1f(v1);
        H[orow0 * ND + (tx << 2) + c] = v0;
        H[(orow0 + 1) * ND + (tx << 2) + c] = v1;
    }
}

extern "C" void kernel_launch(void* const* d_in, const int* in_sizes, int n_in,
                              void* d_out, int out_size, void* d_ws, size_t ws_size,
                              hipStream_t stream) {
    const float* A  = (const float*)d_in[0];   // [8,2048,2048]
    const float* X  = (const float*)d_in[1];   // [8,2048,64]
    const float* Ws = (const float*)d_in[2];   // [64,64]
    const float* a  = (const float*)d_in[3];   // [128,1]
    float* H = (float*)d_out;                  // [8,2048,64]

    char* ws = (char*)d_ws;
    float* Wh = (float*)ws;                               // 4 MiB
    float* sv = (float*)(ws + (size_t)8 * 2048 * 64 * 4); // 64 KiB
    float* tv = sv + 8 * 2048;                            // 64 KiB

    gat_stage1<<<4096, 256, 0, stream>>>(X, Ws, a, Wh, sv, tv);
    gat_stage2<<<512, 256, 0, stream>>>(A, Wh, sv, tv, H);
}

// Round 2
// 56.211 us; speedup vs baseline: 3.1062x; 3.1062x over previous
//
#include <hip/hip_runtime.h>
#include <math.h>

typedef float f32x16 __attribute__((ext_vector_type(16)));
typedef __bf16 bf16x8 __attribute__((ext_vector_type(8)));

#define N_NODES 2048

__device__ __forceinline__ void gload16(const void* g, void* l) {
    __builtin_amdgcn_global_load_lds(
        (__attribute__((address_space(1))) void*)(uintptr_t)g,
        (__attribute__((address_space(3))) void*)l, 16, 0, 0);
}

__device__ __forceinline__ float elu1(float v) { return v > 0.f ? v : expm1f(v); }

// Stage 1: Wh = X@Ws; emit whT_hi/whT_lo (bf16, d-major, XOR-swizzled rows) + s,t scalars.
__global__ __launch_bounds__(256) void gat_stage1(
    const float* __restrict__ X, const float* __restrict__ Ws, const float* __restrict__ av,
    __bf16* __restrict__ whT_hi, __bf16* __restrict__ whT_lo,
    float* __restrict__ sv, float* __restrict__ tvv) {
    __shared__ float wsT[64][68];
    __shared__ float xr[4][64];
    int tid = threadIdx.x;
#pragma unroll
    for (int k = 0; k < 16; ++k) {
        int idx = k * 256 + tid;
        wsT[idx & 63][idx >> 6] = Ws[idx];
    }
    int wave = tid >> 6, lane = tid & 63;
    int row = blockIdx.x * 4 + wave;            // global node 0..16383
    xr[wave][lane] = X[(long)row * 64 + lane];
    __syncthreads();
    float acc = 0.f;
#pragma unroll
    for (int f = 0; f < 64; f += 4) {
        float4 xv = *reinterpret_cast<const float4*>(&xr[wave][f]);
        float4 wv = *reinterpret_cast<const float4*>(&wsT[lane][f]);
        acc += xv.x * wv.x + xv.y * wv.y + xv.z * wv.z + xv.w * wv.w;
    }
    __bf16 hi = (__bf16)acc;
    __bf16 lo = (__bf16)(acc - (float)hi);
    int b = row >> 11, jn = row & 2047, d = lane;
    // physical index jn ^ ((d&7)<<3) == byte swizzle ((jn*2) ^ ((d&7)<<4))
    long gidx = ((long)(b * 64 + d) << 11) + (jn ^ ((d & 7) << 3));
    whT_hi[gidx] = hi;
    whT_lo[gidx] = lo;
    float s = acc * av[lane];
    float t2 = acc * av[64 + lane];
#pragma unroll
    for (int off = 32; off; off >>= 1) {
        s += __shfl_xor(s, off, 64);
        t2 += __shfl_xor(t2, off, 64);
    }
    if (lane == 0) { sv[row] = s; tvv[row] = t2; }
}

// Stage 2: fused masked-softmax attention via MFMA.
// 512 threads (8 waves), TI=64 output rows, chunks of 64 j.
// Wave wid: ih=wid&1 (i-half), dh=(wid>>1)&1 (d-half), js=wid>>2 (j-sub-half of chunk).
// whT LDS triple-buffered (hi+lo 16KB each), wt double-buffered: ONE barrier/chunk.
template<int SPLIT, bool DIRECT>
__global__ __launch_bounds__(512, 4) void gat_stage2(
    const float* __restrict__ A, const __bf16* __restrict__ whT_hi, const __bf16* __restrict__ whT_lo,
    const float* __restrict__ sv, const float* __restrict__ tvv,
    float* __restrict__ numw, float* __restrict__ denw, float* __restrict__ H) {
    __shared__ __align__(16) char lds[65536];
    // layout: whT bufs [3] x 16KB at 0/16384/32768 (hi at +0, lo at +8192)
    //         wt bufs [2] x 8KB at 49152/57344; den_lds reuses 49152 post-loop;
    //         numl (64x64 f32) reuses lds+0 in epilogue.
    int tid = threadIdx.x;
    int nb = gridDim.x;
    int bid = ((int)blockIdx.x & 7) * (nb >> 3) + ((int)blockIdx.x >> 3);  // XCD chunking
    int b = (bid >> 5) & 7;
    int it = bid & 31;
    int sp = bid >> 8;                       // 0..SPLIT-1
    int i0 = it * 64;
    int jbase = sp * (N_NODES / SPLIT);
    const int NC = N_NODES / SPLIT / 64;

    int jl = tid & 63, ig = tid >> 6;        // phase-A mapping; ig == wave id
    // staging mapping: one 16B unit per thread (hi) + one (lo)
    int sd = tid >> 3, sseg = tid & 7;
    const __bf16* srcHi = whT_hi + (((long)(b * 64 + sd)) << 11) + jbase + sseg * 8;
    const __bf16* srcLo = whT_lo + (((long)(b * 64 + sd)) << 11) + jbase + sseg * 8;
    int ldsWaveOff = (tid >> 6) * 1024;

    float s_reg[8], den_p[8];
    const float* svb = sv + b * N_NODES + i0 + ig;
#pragma unroll
    for (int p = 0; p < 8; ++p) { s_reg[p] = svb[p * 8]; den_p[p] = 0.f; }
    const float* Abase = A + ((long)(b * N_NODES + i0 + ig) * N_NODES) + jbase + jl;
    const float* tb = tvv + b * N_NODES + jbase + jl;

    f32x16 acc;
#pragma unroll
    for (int r = 0; r < 16; ++r) acc[r] = 0.f;

    float a_cur[8], a_nxt[8], t_cur, t_nxt;
    // prologue: stage chunk 0, load A chunk 0
    {
        char* dst = lds + 0 * 16384 + ldsWaveOff;
        gload16(srcHi, dst);
        gload16(srcLo, dst + 8192);
    }
#pragma unroll
    for (int p = 0; p < 8; ++p) a_cur[p] = Abase[p * 8 * N_NODES];
    t_cur = tb[0];

    int wid = ig;
    int ihh = (wid & 1) * 32, dhh = ((wid >> 1) & 1) * 32, jss = (wid >> 2) * 32;
    int iA = ihh + (jl & 31);
    int dB = dhh + (jl & 31);
    int swzA = (iA & 7) << 4, swzB = (dB & 7) << 4;
    int kreg = (jl >> 5) * 16;               // byte offset of this lane's 8-elem k-group

#pragma unroll 1
    for (int c = 0; c < NC; ++c) {
        if (c + 1 < NC) {                     // prefetch whT chunk c+1 (buffer (c+1)%3)
            char* dst = lds + ((c + 1) % 3) * 16384 + ldsWaveOff;
            gload16(srcHi + (c + 1) * 64, dst);
            gload16(srcLo + (c + 1) * 64, dst + 8192);
        }
        // phase A: w = A ? exp(leaky(s+t)) : 0, bf16, swizzled store to wt[c&1]
        char* wt = lds + 49152 + (c & 1) * 8192;
        int swzW = (ig & 7) << 4;            // (i&7) == ig for i = p*8+ig
#pragma unroll
        for (int p = 0; p < 8; ++p) {
            int i = p * 8 + ig;
            float e = s_reg[p] + t_cur;
            e = fmaxf(e, 0.2f * e);
            float wv = a_cur[p] > 0.f ? __expf(e) : 0.f;
            __bf16 wb = (__bf16)wv;
            den_p[p] += (float)wb;
            *reinterpret_cast<__bf16*>(wt + i * 128 + ((jl * 2) ^ swzW)) = wb;
        }
        if (c + 1 < NC) {                     // prefetch A chunk c+1
#pragma unroll
            for (int p = 0; p < 8; ++p) a_nxt[p] = Abase[(c + 1) * 64 + p * 8 * N_NODES];
            t_nxt = tb[(c + 1) * 64];
        }
        __syncthreads();
        // MFMA phase: 2 K-steps x (P@hi + P@lo)
        char* whb = lds + (c % 3) * 16384;
        char* wtb = lds + 49152 + (c & 1) * 8192;
#pragma unroll
        for (int ks = 0; ks < 2; ++ks) {
            int jby = (jss + ks * 16) * 2 + kreg;     // byte offset within 128B row
            bf16x8 af = *reinterpret_cast<const bf16x8*>(wtb + iA * 128 + (jby ^ swzA));
            bf16x8 bh = *reinterpret_cast<const bf16x8*>(whb + dB * 128 + (jby ^ swzB));
            bf16x8 bl = *reinterpret_cast<const bf16x8*>(whb + 8192 + dB * 128 + (jby ^ swzB));
            acc = __builtin_amdgcn_mfma_f32_32x32x16_bf16(af, bh, acc, 0, 0, 0);
            acc = __builtin_amdgcn_mfma_f32_32x32x16_bf16(af, bl, acc, 0, 0, 0);
        }
        if (c + 1 < NC) {
#pragma unroll
            for (int p = 0; p < 8; ++p) a_cur[p] = a_nxt[p];
            t_cur = t_nxt;
        }
    }

    // denominator: reduce den_p over the 64 jl lanes of each wave
    float* den_lds = (float*)(lds + 49152);   // wt buf0: free (last MFMA used wt buf1)
#pragma unroll
    for (int p = 0; p < 8; ++p) {
#pragma unroll
        for (int off = 32; off; off >>= 1) den_p[p] += __shfl_xor(den_p[p], off, 64);
    }
    if ((tid & 63) == 0) {
#pragma unroll
        for (int p = 0; p < 8; ++p) den_lds[p * 8 + wid] = den_p[p];
    }
    __syncthreads();                           // all MFMA reads done -> lds+0 reusable
    // combine js=0 / js=1 partials in LDS: numl[64][64]
    float* numl = (float*)lds;
    int colD = dhh + (jl & 31);
    int rbase = ihh + 4 * (jl >> 5);
    if (wid < 4) {
#pragma unroll
        for (int r = 0; r < 16; ++r) numl[(rbase + (r & 3) + 8 * (r >> 2)) * 64 + colD] = acc[r];
    }
    __syncthreads();
    if (wid >= 4) {
#pragma unroll
        for (int r = 0; r < 16; ++r) numl[(rbase + (r & 3) + 8 * (r >> 2)) * 64 + colD] += acc[r];
    }
    __syncthreads();
    // output: each thread 8 floats of the 64x64 tile
    int row = tid >> 3, colb = (tid & 7) * 8;
    float4 n0 = *reinterpret_cast<float4*>(&numl[row * 64 + colb]);
    float4 n1 = *reinterpret_cast<float4*>(&numl[row * 64 + colb + 4]);
    if (DIRECT) {
        float dinv = 1.f / den_lds[row];
        float4 o0, o1;
        o0.x = elu1(n0.x * dinv); o0.y = elu1(n0.y * dinv);
        o0.z = elu1(n0.z * dinv); o0.w = elu1(n0.w * dinv);
        o1.x = elu1(n1.x * dinv); o1.y = elu1(n1.y * dinv);
        o1.z = elu1(n1.z * dinv); o1.w = elu1(n1.w * dinv);
        float* Hrow = H + ((long)(b * N_NODES + i0 + row) * 64 + colb);
        *reinterpret_cast<float4*>(Hrow) = o0;
        *reinterpret_cast<float4*>(Hrow + 4) = o1;
    } else {
        float* nrow = numw + (long)sp * (8L * N_NODES * 64) + ((long)(b * N_NODES + i0 + row) * 64 + colb);
        *reinterpret_cast<float4*>(nrow) = n0;
        *reinterpret_cast<float4*>(nrow + 4) = n1;
        if (tid < 64) denw[sp * 16384 + b * N_NODES + i0 + tid] = den_lds[tid];
    }
}

// Combine the 2 j-split partials: H = elu((n0+n1)/(d0+d1))
__global__ __launch_bounds__(256) void gat_combine(
    const float* __restrict__ numw, const float* __restrict__ denw, float* __restrict__ H) {
    int f4 = blockIdx.x * 256 + threadIdx.x;   // 262144 float4s
    long e0 = (long)f4 * 4;
    int row = f4 >> 4;
    float4 n0 = *reinterpret_cast<const float4*>(numw + e0);
    float4 n1 = *reinterpret_cast<const float4*>(numw + 8L * N_NODES * 64 + e0);
    float dinv = 1.f / (denw[row] + denw[16384 + row]);
    float4 o;
    o.x = elu1((n0.x + n1.x) * dinv);
    o.y = elu1((n0.y + n1.y) * dinv);
    o.z = elu1((n0.z + n1.z) * dinv);
    o.w = elu1((n0.w + n1.w) * dinv);
    *reinterpret_cast<float4*>(H + e0) = o;
}

extern "C" void kernel_launch(void* const* d_in, const int* in_sizes, int n_in,
                              void* d_out, int out_size, void* d_ws, size_t ws_size,
                              hipStream_t stream) {
    const float* A  = (const float*)d_in[0];   // [8,2048,2048]
    const float* X  = (const float*)d_in[1];   // [8,2048,64]
    const float* Ws = (const float*)d_in[2];   // [64,64]
    const float* av = (const float*)d_in[3];   // [128,1]
    float* H = (float*)d_out;                  // [8,2048,64]

    char* ws = (char*)d_ws;
    __bf16* whT_hi = (__bf16*)ws;                           // 2 MiB
    __bf16* whT_lo = (__bf16*)(ws + (1L << 21));            // 2 MiB
    float* sv   = (float*)(ws + (1L << 22));                // 64 KiB
    float* tv   = (float*)(ws + (1L << 22) + 65536);        // 64 KiB
    float* denw = (float*)(ws + (1L << 22) + 131072);       // 128 KiB
    float* numw = (float*)(ws + (1L << 22) + 262144);       // 8 MiB
    const size_t need_split = (1L << 22) + 262144 + (8L << 20);

    gat_stage1<<<4096, 256, 0, stream>>>(X, Ws, av, whT_hi, whT_lo, sv, tv);
    if (ws_size >= need_split) {
        gat_stage2<2, false><<<512, 512, 0, stream>>>(A, whT_hi, whT_lo, sv, tv, numw, denw, H);
        gat_combine<<<1024, 256, 0, stream>>>(numw, denw, H);
    } else {
        gat_stage2<1, true><<<256, 512, 0, stream>>>(A, whT_hi, whT_lo, sv, tv, nullptr, nullptr, H);
    }
}

// Round 3
// 46.281 us; speedup vs baseline: 3.7727x; 1.2146x over previous
//
#include <hip/hip_runtime.h>
#include <math.h>

typedef float f32x16 __attribute__((ext_vector_type(16)));
typedef __bf16 bf16x8 __attribute__((ext_vector_type(8)));

#define N_NODES 2048
#define SCHED_FENCE() __builtin_amdgcn_sched_barrier(0)

__device__ __forceinline__ void gload16(const void* g, void* l) {
    __builtin_amdgcn_global_load_lds(
        (__attribute__((address_space(1))) void*)(uintptr_t)g,
        (__attribute__((address_space(3))) void*)l, 16, 0, 0);
}

__device__ __forceinline__ float elu1(float v) { return v > 0.f ? v : expm1f(v); }

// Stage 1: Wh = X@Ws -> whT_hi/lo (bf16, d-major, XOR-swizzled) + s,t.
// Rows-in-lanes, d iterated per wave => coalesced 128B whT row writes.
__global__ __launch_bounds__(256) void gat_stage1(
    const float* __restrict__ X, const float* __restrict__ Ws, const float* __restrict__ av,
    __bf16* __restrict__ whT_hi, __bf16* __restrict__ whT_lo,
    float* __restrict__ sv, float* __restrict__ tvv) {
    __shared__ float xls[64][66];   // [row][f], stride 66: float2-aligned, 2-way banks (free)
    __shared__ float wss[64][64];   // [f][d], uniform broadcast reads
    __shared__ float sls[4][64], tls[4][64];
    int tid = threadIdx.x;
    int b = blockIdx.x >> 5;
    int j0 = (blockIdx.x & 31) * 64;
    const float* Xb = X + ((long)(b * N_NODES + j0)) * 64;
#pragma unroll
    for (int k = 0; k < 4; ++k) {
        int i4 = k * 256 + tid;               // 1024 float4s of X tile
        float4 v = *reinterpret_cast<const float4*>(Xb + i4 * 4);
        int row = i4 >> 4, c = (i4 & 15) * 4;
        *reinterpret_cast<float2*>(&xls[row][c]) = make_float2(v.x, v.y);
        *reinterpret_cast<float2*>(&xls[row][c + 2]) = make_float2(v.z, v.w);
        *reinterpret_cast<float4*>(&wss[0][0] + i4 * 4) = *reinterpret_cast<const float4*>(Ws + i4 * 4);
    }
    __syncthreads();
    int wave = tid >> 6, lane = tid & 63;     // lane = local row (node j0+lane)
    float s_acc = 0.f, t_acc = 0.f;
#pragma unroll 1
    for (int dd = 0; dd < 16; ++dd) {
        int d = wave * 16 + dd;
        float acc = 0.f;
#pragma unroll
        for (int f = 0; f < 64; f += 2) {
            float2 xv = *reinterpret_cast<const float2*>(&xls[lane][f]);
            acc += xv.x * wss[f][d] + xv.y * wss[f + 1][d];
        }
        __bf16 hi = (__bf16)acc;
        __bf16 lo = (__bf16)(acc - (float)hi);
        long gidx = ((long)(b * 64 + d) << 11) + (j0 + (lane ^ ((d & 7) << 3)));
        whT_hi[gidx] = hi;
        whT_lo[gidx] = lo;
        s_acc += acc * av[d];
        t_acc += acc * av[64 + d];
    }
    sls[wave][lane] = s_acc; tls[wave][lane] = t_acc;
    __syncthreads();
    if (tid < 64) {
        sv[b * N_NODES + j0 + tid]  = sls[0][tid] + sls[1][tid] + sls[2][tid] + sls[3][tid];
        tvv[b * N_NODES + j0 + tid] = tls[0][tid] + tls[1][tid] + tls[2][tid] + tls[3][tid];
    }
}

// Stage 2: fused masked-softmax attention via MFMA. 512 threads, TI=64, JT=64.
// ONE raw barrier per chunk; counted waits via G-before-A issue order (compiler
// drains G(c) as a side effect of waiting on a_cur=A(c)). whT x3, wt x2 buffers.
template<int SPLIT, bool DIRECT>
__global__ __launch_bounds__(512, 4) void gat_stage2(
    const float* __restrict__ A, const __bf16* __restrict__ whT_hi, const __bf16* __restrict__ whT_lo,
    const float* __restrict__ sv, const float* __restrict__ tvv,
    float* __restrict__ numw, float* __restrict__ denw, float* __restrict__ H) {
    __shared__ __align__(16) char lds[65536];
    // whT bufs [3] x 16KB at 0/16384/32768 (hi +0, lo +8192); wt [2] x 8KB at 49152/57344.
    int tid = threadIdx.x;
    int nb = gridDim.x;
    int bid = ((int)blockIdx.x & 7) * (nb >> 3) + ((int)blockIdx.x >> 3);
    int b = (bid >> 5) & 7;
    int it = bid & 31;
    int sp = bid >> 8;
    int i0 = it * 64;
    int jbase = sp * (N_NODES / SPLIT);
    const int NC = N_NODES / SPLIT / 64;

    int jl = tid & 63, ig = tid >> 6;
    int sd = tid >> 3, sseg = tid & 7;
    const __bf16* srcHi = whT_hi + (((long)(b * 64 + sd)) << 11) + jbase + sseg * 8;
    const __bf16* srcLo = whT_lo + (((long)(b * 64 + sd)) << 11) + jbase + sseg * 8;
    int ldsWaveOff = (tid >> 6) * 1024;

    float s_reg[8], den_p[8];
    const float* svb = sv + b * N_NODES + i0 + ig;
#pragma unroll
    for (int p = 0; p < 8; ++p) { s_reg[p] = svb[p * 8]; den_p[p] = 0.f; }
    const float* Abase = A + ((long)(b * N_NODES + i0 + ig) * N_NODES) + jbase + jl;
    const float* tb = tvv + b * N_NODES + jbase + jl;

    f32x16 acc;
#pragma unroll
    for (int r = 0; r < 16; ++r) acc[r] = 0.f;

    int wid = ig;
    int ihh = (wid & 1) * 32, dhh = ((wid >> 1) & 1) * 32, jss = (wid >> 2) * 32;
    int iA = ihh + (jl & 31);
    int dB = dhh + (jl & 31);
    int swzA = (iA & 7) << 4, swzB = (dB & 7) << 4;
    int kreg = (jl >> 5) * 16;
    int swzW = (ig & 7) << 4;

    float a0[8], a1[8], t0, t1;
    // prologue: G(0) then A(0) (order matters: G older than A)
    {
        char* dst = lds + ldsWaveOff;
        gload16(srcHi, dst);
        gload16(srcLo, dst + 8192);
    }
    SCHED_FENCE();
#pragma unroll
    for (int p = 0; p < 8; ++p) a0[p] = Abase[p * 8 * N_NODES];
    t0 = tb[0];
    SCHED_FENCE();

#define CHUNK_BODY(c, A_IN, T_IN, A_OUT, T_OUT)                                         \
    {                                                                                    \
        int cn = (c) + 1 < NC ? (c) + 1 : NC - 1;                                        \
        { /* G issue first (must be older than A issue) */                               \
            char* dst = lds + (cn % 3) * 16384 + ldsWaveOff;                             \
            gload16(srcHi + cn * 64, dst);                                               \
            gload16(srcLo + cn * 64, dst + 8192);                                        \
        }                                                                                \
        SCHED_FENCE();                                                                   \
        _Pragma("unroll")                                                                \
        for (int p = 0; p < 8; ++p) A_OUT[p] = Abase[cn * 64 + p * 8 * N_NODES];         \
        T_OUT = tb[cn * 64];                                                             \
        SCHED_FENCE();                                                                   \
        char* wt = lds + 49152 + ((c) & 1) * 8192;                                       \
        _Pragma("unroll")                                                                \
        for (int p = 0; p < 8; ++p) {                                                    \
            int i = p * 8 + ig;                                                          \
            float e = s_reg[p] + T_IN;                                                   \
            e = fmaxf(e, 0.2f * e);                                                      \
            float wv = A_IN[p] > 0.f ? __expf(e) : 0.f;                                  \
            __bf16 wb = (__bf16)wv;                                                      \
            den_p[p] += (float)wb;                                                       \
            *reinterpret_cast<__bf16*>(wt + i * 128 + ((jl * 2) ^ swzW)) = wb;           \
        }                                                                                \
        asm volatile("s_waitcnt lgkmcnt(0)" ::: "memory");                               \
        __builtin_amdgcn_s_barrier();                                                    \
        SCHED_FENCE();                                                                   \
        char* whb = lds + ((c) % 3) * 16384;                                             \
        char* wtb = lds + 49152 + ((c) & 1) * 8192;                                      \
        __builtin_amdgcn_s_setprio(1);                                                   \
        _Pragma("unroll")                                                                \
        for (int ks = 0; ks < 2; ++ks) {                                                 \
            int jby = (jss + ks * 16) * 2 + kreg;                                        \
            bf16x8 af = *reinterpret_cast<const bf16x8*>(wtb + iA * 128 + (jby ^ swzA)); \
            bf16x8 bh = *reinterpret_cast<const bf16x8*>(whb + dB * 128 + (jby ^ swzB)); \
            bf16x8 bl = *reinterpret_cast<const bf16x8*>(whb + 8192 + dB * 128 + (jby ^ swzB)); \
            acc = __builtin_amdgcn_mfma_f32_32x32x16_bf16(af, bh, acc, 0, 0, 0);         \
            acc = __builtin_amdgcn_mfma_f32_32x32x16_bf16(af, bl, acc, 0, 0, 0);         \
        }                                                                                \
        __builtin_amdgcn_s_setprio(0);                                                   \
        SCHED_FENCE();                                                                   \
    }

#pragma unroll 1
    for (int c2 = 0; c2 < NC; c2 += 2) {
        CHUNK_BODY(c2, a0, t0, a1, t1);
        CHUNK_BODY(c2 + 1, a1, t1, a0, t0);
    }
#undef CHUNK_BODY

    float* den_lds = (float*)(lds + 49152);
#pragma unroll
    for (int p = 0; p < 8; ++p) {
#pragma unroll
        for (int off = 32; off; off >>= 1) den_p[p] += __shfl_xor(den_p[p], off, 64);
    }
    if ((tid & 63) == 0) {
#pragma unroll
        for (int p = 0; p < 8; ++p) den_lds[p * 8 + wid] = den_p[p];
    }
    __syncthreads();                           // all MFMA reads done -> lds+0 reusable
    float* numl = (float*)lds;
    int colD = dhh + (jl & 31);
    int rbase = ihh + 4 * (jl >> 5);
    if (wid < 4) {
#pragma unroll
        for (int r = 0; r < 16; ++r) numl[(rbase + (r & 3) + 8 * (r >> 2)) * 64 + colD] = acc[r];
    }
    __syncthreads();
    if (wid >= 4) {
#pragma unroll
        for (int r = 0; r < 16; ++r) numl[(rbase + (r & 3) + 8 * (r >> 2)) * 64 + colD] += acc[r];
    }
    __syncthreads();
    int row = tid >> 3, colb = (tid & 7) * 8;
    float4 n0 = *reinterpret_cast<float4*>(&numl[row * 64 + colb]);
    float4 n1 = *reinterpret_cast<float4*>(&numl[row * 64 + colb + 4]);
    if (DIRECT) {
        float dinv = 1.f / den_lds[row];
        float4 o0, o1;
        o0.x = elu1(n0.x * dinv); o0.y = elu1(n0.y * dinv);
        o0.z = elu1(n0.z * dinv); o0.w = elu1(n0.w * dinv);
        o1.x = elu1(n1.x * dinv); o1.y = elu1(n1.y * dinv);
        o1.z = elu1(n1.z * dinv); o1.w = elu1(n1.w * dinv);
        float* Hrow = H + ((long)(b * N_NODES + i0 + row) * 64 + colb);
        *reinterpret_cast<float4*>(Hrow) = o0;
        *reinterpret_cast<float4*>(Hrow + 4) = o1;
    } else {
        float* nrow = numw + (long)sp * (8L * N_NODES * 64) + ((long)(b * N_NODES + i0 + row) * 64 + colb);
        *reinterpret_cast<float4*>(nrow) = n0;
        *reinterpret_cast<float4*>(nrow + 4) = n1;
        if (tid < 64) denw[sp * 16384 + b * N_NODES + i0 + tid] = den_lds[tid];
    }
}

__global__ __launch_bounds__(256) void gat_combine(
    const float* __restrict__ numw, const float* __restrict__ denw, float* __restrict__ H) {
    int f4 = blockIdx.x * 256 + threadIdx.x;
    long e0 = (long)f4 * 4;
    int row = f4 >> 4;
    float4 n0 = *reinterpret_cast<const float4*>(numw + e0);
    float4 n1 = *reinterpret_cast<const float4*>(numw + 8L * N_NODES * 64 + e0);
    float dinv = 1.f / (denw[row] + denw[16384 + row]);
    float4 o;
    o.x = elu1((n0.x + n1.x) * dinv);
    o.y = elu1((n0.y + n1.y) * dinv);
    o.z = elu1((n0.z + n1.z) * dinv);
    o.w = elu1((n0.w + n1.w) * dinv);
    *reinterpret_cast<float4*>(H + e0) = o;
}

extern "C" void kernel_launch(void* const* d_in, const int* in_sizes, int n_in,
                              void* d_out, int out_size, void* d_ws, size_t ws_size,
                              hipStream_t stream) {
    const float* A  = (const float*)d_in[0];   // [8,2048,2048]
    const float* X  = (const float*)d_in[1];   // [8,2048,64]
    const float* Ws = (const float*)d_in[2];   // [64,64]
    const float* av = (const float*)d_in[3];   // [128,1]
    float* H = (float*)d_out;                  // [8,2048,64]

    char* ws = (char*)d_ws;
    __bf16* whT_hi = (__bf16*)ws;                           // 2 MiB
    __bf16* whT_lo = (__bf16*)(ws + (1L << 21));            // 2 MiB
    float* sv   = (float*)(ws + (1L << 22));                // 64 KiB
    float* tv   = (float*)(ws + (1L << 22) + 65536);        // 64 KiB
    float* denw = (float*)(ws + (1L << 22) + 131072);       // 128 KiB
    float* numw = (float*)(ws + (1L << 22) + 262144);       // 8 MiB
    const size_t need_split = (1L << 22) + 262144 + (8L << 20);

    gat_stage1<<<256, 256, 0, stream>>>(X, Ws, av, whT_hi, whT_lo, sv, tv);
    if (ws_size >= need_split) {
        gat_stage2<2, false><<<512, 512, 0, stream>>>(A, whT_hi, whT_lo, sv, tv, numw, denw, H);
        gat_combine<<<1024, 256, 0, stream>>>(numw, denw, H);
    } else {
        gat_stage2<1, true><<<256, 512, 0, stream>>>(A, whT_hi, whT_lo, sv, tv, nullptr, nullptr, H);
    }
}